// Round 6
// baseline (418.653 us; speedup 1.0000x reference)
//
#include <hip/hip_runtime.h>

#define M 2048
#define N 131072
#define D 256

#define SLICE_G 64                     // 16-row v-tiles per slice (1024 n per slice)
#define NSLICE  (N / (SLICE_G * 16))   // 128
#define GEN     8                      // tiles per generation (barrier cadence)
#define NGEN    (SLICE_G / GEN)        // 8
#define NQBLK   4                      // 4 q-blocks x 512 rows
#define BIAS    1024.0f                // score = vsq+BIAS-2qv > 0 -> uint-sortable bits

typedef __attribute__((ext_vector_type(8))) _Float16 half8;  // 8 f16 (4 VGPRs)
typedef __attribute__((ext_vector_type(8))) short short8;
typedef __attribute__((ext_vector_type(4))) float f32x4;     // MFMA acc
typedef unsigned long long ull;

__device__ __forceinline__ ull pack_key(float score, unsigned idx) {
    unsigned u = __float_as_uint(score);
    u = (u & 0x80000000u) ? ~u : (u | 0x80000000u);
    return ((ull)u << 32) | idx;
}

// ---------------- Kernel A: q -> f16 frag-linear (tiny: 128 blocks, 1MB) -------------
__global__ __launch_bounds__(256) void q_convert(const float* __restrict__ q,
                                                 short* __restrict__ qf) {
    const int g    = blockIdx.x;
    const int t    = threadIdx.x;
    const int w    = t >> 6;
    const int l    = t & 63;
    const int quad = (l >> 4) & 3;
    const int tx   = l & 15;

    const float* src = q + (size_t)g * 4096;
#pragma unroll
    for (int h = 0; h < 2; ++h) {
        const int c = w + h * 4;
        const float* p = src + tx * 256 + c * 32 + quad * 8;   // contiguous 32B/lane
        const float4 f0 = *(const float4*)p;
        const float4 f1 = *(const float4*)(p + 4);
        half8 hh;
        hh[0] = (_Float16)f0.x; hh[1] = (_Float16)f0.y;
        hh[2] = (_Float16)f0.z; hh[3] = (_Float16)f0.w;
        hh[4] = (_Float16)f1.x; hh[5] = (_Float16)f1.y;
        hh[6] = (_Float16)f1.z; hh[7] = (_Float16)f1.w;
        *(short8*)(qf + ((size_t)g * 8 + c) * 512 + l * 8) = *(short8*)&hh;
    }
}

// ---------------- Kernel B: FUSED, 1 wave/SIMD, 512-reg budget, NO SPILL -------------
// Root cause of R0-R5's low MfmaUtil: register pool is 512/SIMD; 2 waves/SIMD caps a
// wave at 256 combined VGPR+AGPR; our working set (~300) spilled deterministically
// (WRITE_SIZE 16-75MB exact). Fix: 256-thread blocks, __launch_bounds__(256,1) ->
// 1 wave/SIMD, 512 regs/wave. Each wave owns 128 q-rows: aq[8][8]=256 regs (AGPR file
// exactly), acc 32 + best 32 + stage 16 + addr ~40 in VGPRs. ~150 regs slack.
// Per tile per SIMD: 64 MFMA = ~1242 cyc vs LDS/CU 40KB = ~400 cyc -> MFMA-bound 3x.
// Generation pipeline: 1 barrier per 8 tiles; per-tile loads (4 float4) issued at body
// top -> ~1300cyc cover > 900cyc HBM latency. LDS 16B/lane linear (0-conflict proven).
__global__ __launch_bounds__(256, 1) void dist_argmin_fused(const short* __restrict__ qf,
                                                            const float* __restrict__ v,
                                                            ull* __restrict__ keys1,
                                                            ull* __restrict__ keys2) {
    __shared__ short bt[2][GEN][8 * 512];     // 128 KB: [gen-buf][tile][chunk*512+lane*8]
    __shared__ float vsq_s[2][GEN][16][4];    // 4 KB:   [gen-buf][tile][tx][wave]

    const int tid  = threadIdx.x;
    const int lane = tid & 63;
    const int w    = tid >> 6;               // 0..3: wave stages chunks 2w, 2w+1
    const int tx   = lane & 15;
    const int quad = (lane >> 4) & 3;

    // XCD swizzle: 512 blocks; lb%8 = XCD; consecutive s_ = same slice's 4 qblks
    const int lb    = blockIdx.x;
    const int xcd   = lb & 7;
    const int s_    = lb >> 3;               // 0..63 within XCD
    const int slice = xcd * 16 + (s_ >> 2);
    const int qblk  = s_ & 3;

    const int qb0 = qblk * 512 + w * 128;    // wave's first q-row (128 rows)
    const int sg0 = slice * SLICE_G;

    // Prologue: A-frags from f16 qf (L2-hot), 64 x b128 loads -> 256 regs (AGPR file)
    half8 aq[8][8];
#pragma unroll
    for (int mt = 0; mt < 8; ++mt)
#pragma unroll
        for (int c = 0; c < 8; ++c)
            aq[mt][c] = *(const half8*)(qf + ((size_t)((qb0 >> 4) + mt) * 8 + c) * 512 + lane * 8);

    unsigned best[32];
#pragma unroll
    for (int i = 0; i < 32; ++i) best[i] = 0xFFFFFFFFu;

    // wave's staging source: row tx, chunks 2w..2w+1 -> k = w*64 .. w*64+63
    const float* vp = v + ((size_t)sg0 * 16 + tx) * 256 + w * 64 + quad * 8;

    auto cvtwrite = [&](int buf, int t, const float4& f00, const float4& f01,
                        const float4& f10, const float4& f11) {
        float s = f00.x * f00.x + f00.y * f00.y + f00.z * f00.z + f00.w * f00.w;
        s = fmaf(f01.x, f01.x, s); s = fmaf(f01.y, f01.y, s);
        s = fmaf(f01.z, f01.z, s); s = fmaf(f01.w, f01.w, s);
        s = fmaf(f10.x, f10.x, s); s = fmaf(f10.y, f10.y, s);
        s = fmaf(f10.z, f10.z, s); s = fmaf(f10.w, f10.w, s);
        s = fmaf(f11.x, f11.x, s); s = fmaf(f11.y, f11.y, s);
        s = fmaf(f11.z, f11.z, s); s = fmaf(f11.w, f11.w, s);
        half8 h0, h1;
        h0[0] = (_Float16)f00.x; h0[1] = (_Float16)f00.y;
        h0[2] = (_Float16)f00.z; h0[3] = (_Float16)f00.w;
        h0[4] = (_Float16)f01.x; h0[5] = (_Float16)f01.y;
        h0[6] = (_Float16)f01.z; h0[7] = (_Float16)f01.w;
        h1[0] = (_Float16)f10.x; h1[1] = (_Float16)f10.y;
        h1[2] = (_Float16)f10.z; h1[3] = (_Float16)f10.w;
        h1[4] = (_Float16)f11.x; h1[5] = (_Float16)f11.y;
        h1[6] = (_Float16)f11.z; h1[7] = (_Float16)f11.w;
        *(short8*)&bt[buf][t][(2 * w) * 512 + lane * 8]     = *(short8*)&h0;
        *(short8*)&bt[buf][t][(2 * w + 1) * 512 + lane * 8] = *(short8*)&h1;
        s += __shfl_xor(s, 16, 64);
        s += __shfl_xor(s, 32, 64);          // row-tx sumsq over this wave's 64 k
        if (lane < 16) vsq_s[buf][t][lane][w] = s;
    };

    auto compute = [&](int buf, int t, int g) {
        const float4 p0 = *(const float4*)&vsq_s[buf][t][tx][0];
        const float vsqr = ((p0.x + p0.y) + (p0.z + p0.w)) + BIAS;
        f32x4 acc[8];
#pragma unroll
        for (int i = 0; i < 8; ++i) acc[i] = (f32x4){0.f, 0.f, 0.f, 0.f};
        __builtin_amdgcn_s_setprio(1);
#pragma unroll
        for (int c = 0; c < 8; ++c) {
            const half8 b = *(const half8*)&bt[buf][t][c * 512 + lane * 8];
#pragma unroll
            for (int mt = 0; mt < 8; ++mt)
                acc[mt] = __builtin_amdgcn_mfma_f32_16x16x32_f16(aq[mt][c], b, acc[mt], 0, 0, 0);
        }
        __builtin_amdgcn_s_setprio(0);
#pragma unroll
        for (int mt = 0; mt < 8; ++mt)
#pragma unroll
            for (int r = 0; r < 4; ++r) {
                const float sc = fmaf(-2.f, acc[mt][r], vsqr);
                const unsigned key = (__float_as_uint(sc) & 0xFFFFFFC0u) | (unsigned)g;
                const int sl = mt * 4 + r;
                best[sl] = key < best[sl] ? key : best[sl];
            }
    };

    // Fill generation 0 (unroll 1: keeps in-flight staging at 4 float4)
#pragma unroll 1
    for (int t = 0; t < GEN; ++t) {
        const float* p = vp + (size_t)t * 4096;
        const float4 f00 = *(const float4*)p;
        const float4 f01 = *(const float4*)(p + 4);
        const float4 f10 = *(const float4*)(p + 32);
        const float4 f11 = *(const float4*)(p + 36);
        cvtwrite(0, t, f00, f01, f10, f11);
    }
    __syncthreads();

    int buf = 0;
    for (int gen = 0; gen < NGEN; ++gen) {
        const int gbase = gen * GEN;
        if (gen + 1 < NGEN) {
#pragma unroll 1
            for (int t = 0; t < GEN; ++t) {
                const float* p = vp + (size_t)(gbase + GEN + t) * 4096;
                const float4 f00 = *(const float4*)p;         // issued before compute:
                const float4 f01 = *(const float4*)(p + 4);   // ~1300 cyc of MFMA cover
                const float4 f10 = *(const float4*)(p + 32);
                const float4 f11 = *(const float4*)(p + 36);
                compute(buf, t, gbase + t);
                cvtwrite(buf ^ 1, t, f00, f01, f10, f11);
            }
        } else {
#pragma unroll 1
            for (int t = 0; t < GEN; ++t) compute(buf, t, gbase + t);
        }
        __syncthreads();                     // one barrier per 8-tile generation
        buf ^= 1;
    }

    // Epilogue: per slot, min across 16 tx lanes; recover (g, tx); top-2 insert.
#pragma unroll
    for (int mt = 0; mt < 8; ++mt)
#pragma unroll
        for (int r = 0; r < 4; ++r) {
            const int sl = mt * 4 + r;
            unsigned k = best[sl];
#pragma unroll
            for (int off = 8; off; off >>= 1) {
                const unsigned o = (unsigned)__shfl_xor((int)k, off, 16);
                k = o < k ? o : k;
            }
            const ull bal = __ballot(best[sl] == k);
            const unsigned grp = (unsigned)((bal >> (quad * 16)) & 0xFFFFull);
            const int wtx = __ffs((int)grp) - 1;
            const unsigned n = (unsigned)((sg0 + (int)(k & 63u)) * 16 + wtx);
            if (tx == 0) {
                const int row = qb0 + mt * 16 + quad * 4 + r;
                const ull key64 = ((ull)k << 32) | n;
                const ull old = atomicMin(&keys1[row], key64);
                const ull loser = (key64 < old) ? old : key64;
                if (loser != ~0ull) atomicMin(&keys2[row], loser);
            }
        }
}

// ---------------- Kernel C: exact fp32 rescore of approx top-2 ----------------
__global__ __launch_bounds__(256) void rescore_kernel(const float* __restrict__ q,
                                                      const float* __restrict__ v,
                                                      const ull* __restrict__ keys1,
                                                      const ull* __restrict__ keys2,
                                                      int* __restrict__ out) {
    const int qi   = blockIdx.x * 4 + (threadIdx.x >> 6);
    const int lane = threadIdx.x & 63;
    const float4 qv = *(const float4*)(q + (size_t)qi * D + lane * 4);
    ull best = ~0ull;
    ull cand[2];
    cand[0] = keys1[qi];
    cand[1] = keys2[qi];
#pragma unroll
    for (int c = 0; c < 2; ++c) {
        if (cand[c] == ~0ull) continue;
        const unsigned idx = (unsigned)cand[c];
        const float4 vv = *(const float4*)(v + (size_t)idx * D + lane * 4);
        float s1 = vv.x * vv.x + vv.y * vv.y + vv.z * vv.z + vv.w * vv.w;   // ||v||^2
        float s2 = qv.x * vv.x + qv.y * vv.y + qv.z * vv.z + qv.w * vv.w;   // q.v
#pragma unroll
        for (int off = 32; off; off >>= 1) {
            s1 += __shfl_xor(s1, off, 64);
            s2 += __shfl_xor(s2, off, 64);
        }
        const float dist = fmaf(-2.0f, s2, s1);   // exact fp32 (sans ||q||^2)
        const ull key = pack_key(dist, idx);
        best = best < key ? best : key;
    }
    if (lane == 0) out[qi] = (int)(unsigned)(best & 0xFFFFFFFFull);
}

extern "C" void kernel_launch(void* const* d_in, const int* in_sizes, int n_in,
                              void* d_out, int out_size, void* d_ws, size_t ws_size,
                              hipStream_t stream) {
    const float* q = (const float*)d_in[0];
    const float* v = (const float*)d_in[1];
    int* out = (int*)d_out;

    ull* keys1 = (ull*)d_ws;                 // 32KB keys + 1MB qf workspace
    ull* keys2 = keys1 + M;
    short* qf = (short*)(keys2 + M);

    hipMemsetAsync(d_ws, 0xFF, (size_t)2 * M * sizeof(ull), stream);

    q_convert<<<M / 16, 256, 0, stream>>>(q, qf);

    dist_argmin_fused<<<NQBLK * NSLICE, 256, 0, stream>>>(qf, v, keys1, keys2);

    rescore_kernel<<<M / 4, 256, 0, stream>>>(q, v, keys1, keys2, out);
}

// Round 8
// 311.028 us; speedup vs baseline: 1.3460x; 1.3460x over previous
//
#include <hip/hip_runtime.h>

#define M 2048
#define N 131072
#define D 256

#define SLICE_G 64                     // 16-row v-tiles per slice (1024 n per slice)
#define NSLICE  (N / (SLICE_G * 16))   // 128
#define GEN     4                      // tiles per generation (barrier cadence)
#define NGEN    (SLICE_G / GEN)        // 16
#define BIAS    1024.0f                // score = vsq+BIAS-2qv > 0 -> uint-sortable bits

typedef __attribute__((ext_vector_type(8))) _Float16 half8;  // 8 f16 (4 VGPRs)
typedef __attribute__((ext_vector_type(8))) short short8;
typedef __attribute__((ext_vector_type(4))) float f32x4;     // MFMA acc / NT loads
typedef unsigned long long ull;

__device__ __forceinline__ ull pack_key(float score, unsigned idx) {
    unsigned u = __float_as_uint(score);
    u = (u & 0x80000000u) ? ~u : (u | 0x80000000u);
    return ((ull)u << 32) | idx;
}

// async 16B global -> LDS (wave-uniform LDS base; HW adds lane*16; global addr per-lane)
__device__ __forceinline__ void gload_lds16(const void* g, void* l) {
    __builtin_amdgcn_global_load_lds(
        (const __attribute__((address_space(1))) void*)g,
        (__attribute__((address_space(3))) void*)l, 16, 0, 0);
}

// ---------------- Kernel A (fused): V and Q -> f16 FRAGMENT-LINEAR ----------
// R1's proven direct converter + NONTEMPORAL v loads: v fp32 is never re-read at
// volume (dist uses vf), so keep it out of L2/LLC -> vf (64MB) stays LLC-resident
// for dist (FETCH stays ~40MB) and the converter avoids polluting 128MB of LLC.
// vf stores stay cached (dist re-reads them immediately).
__global__ __launch_bounds__(256) void convert_fused(const float* __restrict__ v,
                                                     const float* __restrict__ q,
                                                     short* __restrict__ vf,
                                                     short* __restrict__ qf,
                                                     float* __restrict__ vsqb) {
    __shared__ float part[4][16];

    const int b    = blockIdx.x;
    const bool isV = (b < N / 16);
    const int g    = isV ? b : (b - N / 16);
    const float* x = isV ? v : q;
    short* xf      = isV ? vf : qf;

    const int t    = threadIdx.x;
    const int w    = t >> 6;
    const int l    = t & 63;
    const int quad = (l >> 4) & 3;
    const int tx   = l & 15;

    const float* src = x + (size_t)g * 4096;
    float s = 0.f;
#pragma unroll
    for (int h = 0; h < 2; ++h) {
        const int c = w + h * 4;
        const float* p = src + tx * 256 + c * 32 + quad * 8;   // contiguous 32B/lane
        const f32x4 f0 = __builtin_nontemporal_load((const f32x4*)p);
        const f32x4 f1 = __builtin_nontemporal_load((const f32x4*)p + 1);
        half8 hh;
#pragma unroll
        for (int e = 0; e < 4; ++e) {
            hh[e]     = (_Float16)f0[e];
            hh[e + 4] = (_Float16)f1[e];
            s = fmaf(f0[e], f0[e], s);
            s = fmaf(f1[e], f1[e], s);
        }
        *(short8*)(xf + ((size_t)g * 8 + c) * 512 + l * 8) = *(short8*)&hh;
    }

    if (isV) {
        s += __shfl_xor(s, 16, 64);
        s += __shfl_xor(s, 32, 64);
        if (l < 16) part[w][l] = s;
        __syncthreads();
        if (t < 16) vsqb[g * 16 + t] = part[0][t] + part[1][t] + part[2][t] + part[3][t] + BIAS;
    }
}

// ---------------- Kernel B: R0 wave layout + generation-staged LDS ----------
// R0's 64 q-rows/wave reg-resident structure (134us, MfmaUtil 47%) with ONE change:
// B-tiles staged into LDS via global_load_lds, GEN=4 tiles per barrier (~2500cyc
// cadence vs R1's per-tile 650cyc lockstep). Stage for gen+1 issues BEFORE gen's
// 4 tile-computes -> full-gen cover (>= 2500cyc) for HBM/L2 latency; per-CU L1/L2
// pull drops 4x (tile fetched once per block, not once per wave). Registers
// unchanged from R0 (aq 128 AGPR + ~100 VGPR, fits 256 @ 2 waves/SIMD, no spill).
__global__ __launch_bounds__(256, 2) void dist_argmin_lds(const short* __restrict__ qf,
                                                          const short* __restrict__ vf,
                                                          const float* __restrict__ vsqb,
                                                          ull* __restrict__ keys1,
                                                          ull* __restrict__ keys2) {
    __shared__ short bt[2][GEN][8 * 512];     // 64 KB: [buf][tile][chunk*512+lane*8]

    const int tid  = threadIdx.x;
    const int lane = tid & 63;
    const int w    = tid >> 6;
    const int tx   = lane & 15;
    const int quad = (lane >> 4) & 3;

    // XCD swizzle: 1024 blocks; lb%8 = XCD; each XCD covers its own 16 slices (8 MB)
    const int lb    = blockIdx.x;
    const int xcd   = lb & 7;
    const int s_    = lb >> 3;              // 0..127 within XCD
    const int slice = xcd * 16 + (s_ >> 3);
    const int qblk  = s_ & 7;

    const int qb0 = qblk * 256 + w * 64;    // wave's first q-row (64 rows)
    const int sg0 = slice * SLICE_G;

    half8 aq[4][8];                         // 128 regs (AGPR file), loaded once
#pragma unroll
    for (int mt = 0; mt < 4; ++mt)
#pragma unroll
        for (int c = 0; c < 8; ++c)
            aq[mt][c] = *(const half8*)(qf + ((size_t)((qb0 >> 4) + mt) * 8 + c) * 512 + lane * 8);

    unsigned best[16];
#pragma unroll
    for (int i = 0; i < 16; ++i) best[i] = 0xFFFFFFFFu;

    const short* bsl = vf + (size_t)sg0 * 8 * 512;   // slice base; g-tile = 8KB contiguous
    const float* vp  = vsqb + sg0 * 16 + tx;

    // stage GEN tiles into buf: per tile 8 x 1KB chunks; wave w does chunks w, w+4
    auto stage = [&](int buf, int gbase) {
#pragma unroll
        for (int t = 0; t < GEN; ++t) {
            const short* gs = bsl + (size_t)(gbase + t) * 4096;
#pragma unroll
            for (int i = 0; i < 2; ++i) {
                const int c = w + i * 4;                       // wave-uniform
                gload_lds16(gs + c * 512 + lane * 8, &bt[buf][t][c * 512]);
            }
        }
    };

    auto compute = [&](int buf, int t, int g) {
        const float vsqr = vp[(size_t)g * 16];
        f32x4 acc[4];
#pragma unroll
        for (int i = 0; i < 4; ++i) acc[i] = (f32x4){0.f, 0.f, 0.f, 0.f};
        __builtin_amdgcn_s_setprio(1);
#pragma unroll
        for (int c = 0; c < 8; ++c) {
            const half8 b = *(const half8*)&bt[buf][t][c * 512 + lane * 8];  // linear, 0-conflict
#pragma unroll
            for (int mt = 0; mt < 4; ++mt)
                acc[mt] = __builtin_amdgcn_mfma_f32_16x16x32_f16(aq[mt][c], b, acc[mt], 0, 0, 0);
        }
        __builtin_amdgcn_s_setprio(0);
#pragma unroll
        for (int mt = 0; mt < 4; ++mt)
#pragma unroll
            for (int r = 0; r < 4; ++r) {
                const float sc = fmaf(-2.f, acc[mt][r], vsqr);
                const unsigned key = (__float_as_uint(sc) & 0xFFFFFFC0u) | (unsigned)g;
                const int sl = mt * 4 + r;
                best[sl] = key < best[sl] ? key : best[sl];
            }
    };

    stage(0, 0);
    __syncthreads();                        // vmcnt(0) drained: buf0 ready

    int buf = 0;
    for (int gen = 0; gen < NGEN; ++gen) {
        if (gen + 1 < NGEN) stage(buf ^ 1, (gen + 1) * GEN);  // full-gen prefetch cover
#pragma unroll
        for (int t = 0; t < GEN; ++t) compute(buf, t, gen * GEN + t);
        __syncthreads();                    // one barrier per GEN tiles (drains stage)
        buf ^= 1;
    }

    // Epilogue: per slot, min across 16 tx lanes; recover (g, tx); top-2 insert.
#pragma unroll
    for (int mt = 0; mt < 4; ++mt)
#pragma unroll
        for (int r = 0; r < 4; ++r) {
            const int sl = mt * 4 + r;
            unsigned k = best[sl];
#pragma unroll
            for (int off = 8; off; off >>= 1) {
                const unsigned o = (unsigned)__shfl_xor((int)k, off, 16);
                k = o < k ? o : k;
            }
            const ull bal = __ballot(best[sl] == k);
            const unsigned grp = (unsigned)((bal >> (quad * 16)) & 0xFFFFull);
            const int wtx = __ffs((int)grp) - 1;
            const unsigned n = (unsigned)((sg0 + (int)(k & 63u)) * 16 + wtx);
            if (tx == 0) {
                const int row = qb0 + mt * 16 + quad * 4 + r;
                const ull key64 = ((ull)k << 32) | n;
                const ull old = atomicMin(&keys1[row], key64);
                const ull loser = (key64 < old) ? old : key64;
                if (loser != ~0ull) atomicMin(&keys2[row], loser);
            }
        }
}

// ---------------- Kernel C: exact fp32 rescore of approx top-2 ----------------
__global__ __launch_bounds__(256) void rescore_kernel(const float* __restrict__ q,
                                                      const float* __restrict__ v,
                                                      const ull* __restrict__ keys1,
                                                      const ull* __restrict__ keys2,
                                                      int* __restrict__ out) {
    const int qi   = blockIdx.x * 4 + (threadIdx.x >> 6);
    const int lane = threadIdx.x & 63;
    const float4 qv = *(const float4*)(q + (size_t)qi * D + lane * 4);
    ull best = ~0ull;
    ull cand[2];
    cand[0] = keys1[qi];
    cand[1] = keys2[qi];
#pragma unroll
    for (int c = 0; c < 2; ++c) {
        if (cand[c] == ~0ull) continue;
        const unsigned idx = (unsigned)cand[c];
        const float4 vv = *(const float4*)(v + (size_t)idx * D + lane * 4);
        float s1 = vv.x * vv.x + vv.y * vv.y + vv.z * vv.z + vv.w * vv.w;   // ||v||^2
        float s2 = qv.x * vv.x + qv.y * vv.y + qv.z * vv.z + qv.w * vv.w;   // q.v
#pragma unroll
        for (int off = 32; off; off >>= 1) {
            s1 += __shfl_xor(s1, off, 64);
            s2 += __shfl_xor(s2, off, 64);
        }
        const float dist = fmaf(-2.0f, s2, s1);   // exact fp32 (sans ||q||^2)
        const ull key = pack_key(dist, idx);
        best = best < key ? best : key;
    }
    if (lane == 0) out[qi] = (int)(unsigned)(best & 0xFFFFFFFFull);
}

extern "C" void kernel_launch(void* const* d_in, const int* in_sizes, int n_in,
                              void* d_out, int out_size, void* d_ws, size_t ws_size,
                              hipStream_t stream) {
    const float* q = (const float*)d_in[0];
    const float* v = (const float*)d_in[1];
    int* out = (int*)d_out;

    char* ws = (char*)d_ws;
    ull* keys1 = (ull*)ws;                   ws += (size_t)2 * M * sizeof(ull);
    ull* keys2 = keys1 + M;
    float* vsqb = (float*)ws;                ws += (size_t)N * sizeof(float);
    short* qf = (short*)ws;                  ws += (size_t)M * D * 2;
    short* vf = (short*)ws;                  // 64 MB frag-linear

    hipMemsetAsync(keys1, 0xFF, (size_t)2 * M * sizeof(ull), stream);

    convert_fused<<<N / 16 + M / 16, 256, 0, stream>>>(v, q, vf, qf, vsqb);

    dist_argmin_lds<<<(M / 256) * NSLICE, 256, 0, stream>>>(qf, vf, vsqb, keys1, keys2);

    rescore_kernel<<<M / 4, 256, 0, stream>>>(q, v, keys1, keys2, out);
}